// Round 3
// baseline (73.752 us; speedup 1.0000x reference)
//
#include <hip/hip_runtime.h>

typedef float v2f __attribute__((ext_vector_type(2)));
typedef float v4f __attribute__((ext_vector_type(4)));

#define EPS 1e-7f
#define LDS_ROWS 62   // 56 + 6 halo
#define LDS_COLS 64   // v2f entries per row (row stride 512 B)

// mantissa_map: (|v|+eps) -> mantissa m in [1,2); result = m>=1.5 ? m/2 : m  -> [0.75,1.5)
__device__ __forceinline__ float mant_map(float v) {
    float a = fabsf(v) + EPS;
    unsigned int bi = __float_as_uint(a);
    float m = __uint_as_float((bi & 0x007FFFFFu) | 0x3F800000u);
    return (m >= 1.5f) ? 0.5f * m : m;
}

// Pre-kernel: per-channel tap constants {B = w/M2, C = B*(M2-1)} into workspace.
__global__ __launch_bounds__(64) void wprep_kernel(const float* __restrict__ w,
                                                   v2f* __restrict__ wt) {
    int t = blockIdx.x * 64 + threadIdx.x;
    if (t < 192 * 49) {
        float wv = w[t];
        float M2 = mant_map(wv);
        float B = wv / M2;
        wt[t] = (v2f){B, B * (M2 - 1.0f)};
    }
}

// One block per (b,c) plane. Thread (lx,ty) computes output cols {2lx, 2lx+1},
// rows ty*7 .. ty*7+6. Row reads are 4x ds_read_b128 (16B-aligned since x0 even).
__global__ __launch_bounds__(256) void wconv_kernel(const float* __restrict__ x,
                                                    const v2f* __restrict__ wtab,
                                                    float* __restrict__ out) {
    __shared__ v2f sp[LDS_ROWS][LDS_COLS];  // {u = x, v = x/M1}

    const int lx = threadIdx.x;       // 0..31 (col pair; active if <28)
    const int ty = threadIdx.y;       // 0..7
    const int tid = ty * 32 + lx;
    const int c = blockIdx.x;
    const int b = blockIdx.y;

    const long plane = (long)(b * 192 + c) * (56 * 56);
    const float* xp = x + plane;
    const v2f* wt = wtab + c * 49;    // uniform -> s_load

    // --- stage full plane + halo: sp[r][lc] = input (r-3, lc-3) ---
    for (int idx = tid; idx < LDS_ROWS * LDS_COLS; idx += 256) {
        int r = idx >> 6, lc = idx & 63;
        int ir = r - 3, ic = lc - 3;
        float u = 0.0f;
        if (ir >= 0 && ir < 56 && ic >= 0 && ic < 56)
            u = xp[ir * 56 + ic];
        float v = u * __builtin_amdgcn_rcpf(mant_map(u));  // u==0 -> v==0 (pad contributes 0)
        sp[r][lc] = (v2f){u, v};
    }
    __syncthreads();

    if (lx < 28) {
        const int x0 = lx * 2;        // output col base (even)
        const int rb = ty * 7;        // output row base; sp rows rb..rb+12

        v2f a0[7], a1[7];
        #pragma unroll
        for (int r = 0; r < 7; ++r) { a0[r] = (v2f){0.f, 0.f}; a1[r] = (v2f){0.f, 0.f}; }

        #pragma unroll
        for (int ir2 = 0; ir2 < 13; ++ir2) {
            // 8 pixels (u,v) covering both columns' 7-windows: 4x b128
            const v4f* q = (const v4f*)&sp[rb + ir2][x0];
            v4f q0 = q[0], q1 = q[1], q2 = q[2], q3 = q[3];
            float t[16] = {q0.x, q0.y, q0.z, q0.w, q1.x, q1.y, q1.z, q1.w,
                           q2.x, q2.y, q2.z, q2.w, q3.x, q3.y, q3.z, q3.w};

            #pragma unroll
            for (int ry = 0; ry < 7; ++ry) {
                const int i = ir2 - ry;            // weight row; compile-time resolved
                if (i >= 0 && i <= 6) {
                    const v2f* wr = wt + i * 7;
                    #pragma unroll
                    for (int j = 0; j < 7; ++j) {
                        v2f wc = wr[j];
                        a0[ry] += (v2f){t[2 * j],     t[2 * j + 1]} * wc;  // col x0
                        a1[ry] += (v2f){t[2 * j + 2], t[2 * j + 3]} * wc;  // col x0+1
                    }
                }
            }
        }

        #pragma unroll
        for (int ry = 0; ry < 7; ++ry) {
            float2 o = make_float2(a0[ry].x + a0[ry].y, a1[ry].x + a1[ry].y);
            *(float2*)&out[plane + (rb + ry) * 56 + x0] = o;   // 8B-aligned (x0 even)
        }
    }
}

extern "C" void kernel_launch(void* const* d_in, const int* in_sizes, int n_in,
                              void* d_out, int out_size, void* d_ws, size_t ws_size,
                              hipStream_t stream) {
    const float* x = (const float*)d_in[0];   // (4,192,56,56) fp32
    const float* w = (const float*)d_in[1];   // (192,1,7,7) fp32
    float* out = (float*)d_out;
    v2f* wt = (v2f*)d_ws;                     // 192*49 v2f = 75 KB

    hipLaunchKernelGGL(wprep_kernel, dim3(147), dim3(64), 0, stream, w, wt);
    hipLaunchKernelGGL(wconv_kernel, dim3(192, 4), dim3(32, 8), 0, stream, x, wt, out);
}

// Round 4
// 69.479 us; speedup vs baseline: 1.0615x; 1.0615x over previous
//
#include <hip/hip_runtime.h>

typedef float v2f __attribute__((ext_vector_type(2)));
typedef float v4f __attribute__((ext_vector_type(4)));

#define EPS 1e-7f

// mantissa_map: (|v|+eps) -> mantissa m in [1,2); result = m>=1.5 ? m/2 : m  -> [0.75,1.5)
__device__ __forceinline__ float mant_map(float v) {
    float a = fabsf(v) + EPS;
    unsigned int bi = __float_as_uint(a);
    float m = __uint_as_float((bi & 0x007FFFFFu) | 0x3F800000u);
    return (m >= 1.5f) ? 0.5f * m : m;
}

// Block = (32,4) = 128 threads. One block covers a 28-row x 56-col slab of one
// (b,c) plane. Thread (lx,ty): output cols {2lx,2lx+1}, rows ty*7..ty*7+6.
// out = sum_taps u*B + v*C  with u=x, v=x/M1, B=w/M2, C=B*(M2-1).
__global__ __launch_bounds__(128, 3) void wconv_kernel(const float* __restrict__ x,
                                                       const float* __restrict__ w,
                                                       float* __restrict__ out) {
    __shared__ v2f sp[34][64];   // rows y0-3 .. y0+30, cols -3..60  (17.4 KB)
    __shared__ v2f swt[49];      // {B, C} per tap

    const int lx = threadIdx.x;   // 0..31 (col pair; active if <28)
    const int ty = threadIdx.y;   // 0..3
    const int tid = ty * 32 + lx;
    const int c = blockIdx.x;
    const int b = blockIdx.y;
    const int tz = blockIdx.z;    // 0..1 (28-row slab)

    const int y0 = 28 * tz;
    const int g0 = (tz == 0) ? 0 : 25;    // first real input row staged
    const int l0 = (tz == 0) ? 3 : 0;     // its LDS row
    const int z0 = (tz == 0) ? 0 : 31;    // first of 3 fully-zero LDS rows

    const long plane = (long)(b * 192 + c) * 3136;
    const float* xp = x + plane;

    // --- fused weight prep (per block; redundant but trivial) ---
    if (tid < 49) {
        float wv = w[c * 49 + tid];
        float M2 = mant_map(wv);
        float B = wv / M2;
        swt[tid] = (v2f){B, B * (M2 - 1.0f)};
    }

    // --- halo zero: 3 full rows + side cols of the 31 real rows ---
    for (int t = tid; t < 192; t += 128)
        ((v2f*)sp)[z0 * 64 + t] = (v2f){0.f, 0.f};
    for (int t = tid; t < 248; t += 128) {
        int r = l0 + (t >> 3), k = t & 7;
        int col = (k < 3) ? k : 56 + k;   // cols 0,1,2, 59..63
        sp[r][col] = (v2f){0.f, 0.f};
    }

    // --- interior staging: 31 rows x 14 dword4-quads, branch-free ---
    for (int t = tid; t < 434; t += 128) {
        int r = t / 14, q4 = t % 14;
        v4f u4 = *(const v4f*)(xp + (g0 + r) * 56 + q4 * 4);
        v2f* dst = &sp[l0 + r][3 + q4 * 4];
        dst[0] = (v2f){u4.x, u4.x * __builtin_amdgcn_rcpf(mant_map(u4.x))};
        dst[1] = (v2f){u4.y, u4.y * __builtin_amdgcn_rcpf(mant_map(u4.y))};
        dst[2] = (v2f){u4.z, u4.z * __builtin_amdgcn_rcpf(mant_map(u4.z))};
        dst[3] = (v2f){u4.w, u4.w * __builtin_amdgcn_rcpf(mant_map(u4.w))};
    }
    __syncthreads();

    if (lx < 28) {
        const int x0 = lx * 2;    // output col base (even) -> 16B-aligned LDS reads
        const int rb = ty * 7;    // output row base within slab

        v2f a0[7], a1[7];
        #pragma unroll
        for (int r = 0; r < 7; ++r) { a0[r] = (v2f){0.f, 0.f}; a1[r] = (v2f){0.f, 0.f}; }

        #pragma unroll
        for (int ir = 0; ir < 13; ++ir) {
            const v4f* q = (const v4f*)&sp[rb + ir][x0];
            v4f q0 = q[0], q1 = q[1], q2 = q[2], q3 = q[3];
            v2f p[8] = {{q0.x, q0.y}, {q0.z, q0.w}, {q1.x, q1.y}, {q1.z, q1.w},
                        {q2.x, q2.y}, {q2.z, q2.w}, {q3.x, q3.y}, {q3.z, q3.w}};
            #pragma unroll
            for (int ry = 0; ry < 7; ++ry) {
                const int i = ir - ry;          // weight row; compile-time resolved
                if (i >= 0 && i <= 6) {
                    #pragma unroll
                    for (int j = 0; j < 7; ++j) {
                        v2f wc = swt[i * 7 + j];
                        a0[ry] += p[j] * wc;      // v_pk_fma_f32
                        a1[ry] += p[j + 1] * wc;
                    }
                }
            }
        }

        #pragma unroll
        for (int ry = 0; ry < 7; ++ry) {
            float2 o = make_float2(a0[ry].x + a0[ry].y, a1[ry].x + a1[ry].y);
            *(float2*)&out[plane + (y0 + rb + ry) * 56 + x0] = o;
        }
    }
}

extern "C" void kernel_launch(void* const* d_in, const int* in_sizes, int n_in,
                              void* d_out, int out_size, void* d_ws, size_t ws_size,
                              hipStream_t stream) {
    const float* x = (const float*)d_in[0];   // (4,192,56,56) fp32
    const float* w = (const float*)d_in[1];   // (192,1,7,7) fp32
    float* out = (float*)d_out;

    hipLaunchKernelGGL(wconv_kernel, dim3(192, 4, 2), dim3(32, 4), 0, stream, x, w, out);
}